// Round 7
// baseline (614.688 us; speedup 1.0000x reference)
//
#include <hip/hip_runtime.h>
#include <math.h>

// FrankWolfePolicyImprovement, fused: 4096 problems, one wave (64 lanes) each.
// Phases (single kernel, A resident in LDS throughout):
//   1. anchor QP  (Schur-reduced d=68 ADMM, 80 it, Sinv rows in VGPRs)
//   2. tanh MLP gradient
//   3. LMO QP on row-normalized A (normalization folded into registers)
//   4. blend + store
//
// Round-7 model (from R5 vs R6 evidence): the per-CU LDS pipe is the
// bottleneck -- every wave64 ds_read_b128 (even a wave-uniform broadcast)
// moves 1 KB into the RF (~8-12 cyc); ~9.5K such ops/wave x 16 waves/CU
// ~= 600 us, matching both R5 (clean regs, 22% occ) and R6 (spilled, 42%
// occ) at ~550-600 us. So: cut LDS instructions, not VALU/occupancy.
//  - inversion via register/readlane Gauss-Jordan (R2's proven gj_invert):
//    ZERO LDS (was 2048 b128/wave in sweep version).
//  - arow[32] in registers: kills 1280 spread-b128/wave in the A.x loops.
//  - slack bound rows z3/y3 live in lanes 28..31 (no ds_bpermute shuffles).
//  - NO dynamic indexing into register arrays (build loops stay on LDS).
//  - (64,2): 256-reg budget; ~155 live -> arch ~128 + few cold AGPR copies.

constexpr float SIG  = 1e-6f;
constexpr float C2   = 1.0f / (4.0f + 1e-6f);   // 1/(4+sigma): slack Schur diag
constexpr int   ITRS = 80;
constexpr int   LDA  = 68;                       // LDS stride for A (16B-aligned rows)

__device__ __forceinline__ float rl(float v, int lane) {
  return __uint_as_float(__builtin_amdgcn_readlane(__float_as_uint(v), lane));
}

// v_rcp_f32 + one Newton step: ~full fp32 precision reciprocal.
__device__ __forceinline__ float rcp_nr(float x) {
  float r = __builtin_amdgcn_rcpf(x);
  return r * fmaf(-x, r, 2.0f);
}

// In-place Gauss-Jordan inverse of SPD matrix, column layout with rotation:
// on entry lane j holds Cm[i] = S[i][j]; on exit Cm[i] = Sinv[i][j] (= row j).
// Pivot column via readlane (wave-uniform SGPR lane index) -- VALU pipe only,
// ZERO LDS traffic. Row-rotation fused into the shifted write (p-loop rolled).
__device__ __forceinline__ void gj_invert(float (&Cm)[64], int t) {
#pragma unroll 1
  for (int p = 0; p < 64; ++p) {
    float piv = rcp_nr(rl(Cm[0], p));
    bool  isP = (t == p);
    float sc  = Cm[0] * piv;
    float a    = isP ? (1.0f + piv) : sc;
    float last = isP ? piv          : sc;
#pragma unroll
    for (int m = 1; m < 64; ++m) {
      float s = rl(Cm[m], p);
      Cm[m - 1] = fmaf(-s, a, Cm[m]);
    }
    Cm[63] = last;
  }
}

__global__ __launch_bounds__(64, 2) void fw_kernel(
    const float* __restrict__ xraw, const float* __restrict__ A,
    const float* __restrict__ b, const float* __restrict__ W1,
    const float* __restrict__ W1T, const float* __restrict__ w2,
    float* __restrict__ out) {
  const int n = blockIdx.x, t = threadIdx.x;
  const float* Ap = A + (size_t)n * 2048;

  __shared__ __align__(16) float lsA[32 * LDA];   // 8704 B, raw A (never rewritten)
  __shared__ __align__(16) float sbuf[256];       // 1024 B, multi-purpose
  float* lst1 = sbuf;            // [64]  ADMM t1 broadcast
  float* lsx  = sbuf + 64;       // [64]  ADMM x broadcast
  float* lsv2 = sbuf + 128;      // [32]  ADMM v2 broadcast
  float* lsrn = sbuf + 176;      // [32]  1/rownorm (LMO phase)
  // MLP phase reuses sbuf[0..255] as the u-vector.

  // ---- stage A into LDS (float4 both sides) ----
  const float4* Apv = (const float4*)Ap;
#pragma unroll
  for (int jj = 0; jj < 8; ++jj) {
    float4 a4 = Apv[t + 64 * jj];
    int k = (t >> 4) + 4 * jj;        // row
    int col = 4 * (t & 15);
    *((float4*)&lsA[k * LDA + col]) = a4;
  }
  __syncthreads();

  const int r = t & 31, c0 = (t >> 5) << 5;

  // ================= anchor QP: build S, invert =================
  // S column t: (2+sig)I + A^T A - C2 * As^T As  (As = rows 28..31)
  float Cm[64];
#pragma unroll
  for (int i = 0; i < 64; ++i) Cm[i] = 0.f;
#pragma unroll 1
  for (int k = 0; k < 32; ++k) {
    float wk = (k < 28) ? 1.0f : (1.0f - C2);
    float ak = wk * lsA[k * LDA + t];  // spread read (dynamic k: LDS, not regs)
#pragma unroll
    for (int ii = 0; ii < 16; ++ii) {
      float4 a4 = *((const float4*)&lsA[k * LDA + 4 * ii]);  // broadcast
      Cm[4 * ii + 0] = fmaf(ak, a4.x, Cm[4 * ii + 0]);
      Cm[4 * ii + 1] = fmaf(ak, a4.y, Cm[4 * ii + 1]);
      Cm[4 * ii + 2] = fmaf(ak, a4.z, Cm[4 * ii + 2]);
      Cm[4 * ii + 3] = fmaf(ak, a4.w, Cm[4 * ii + 3]);
    }
  }
#pragma unroll
  for (int i = 0; i < 64; ++i) Cm[i] += (i == t) ? (2.0f + SIG) : 0.0f;

  gj_invert(Cm, t);   // Cm[j] = Sinv[t][j], zero LDS

  // per-lane A fragments (static indices only)
  float acol[32], arow[32];
#pragma unroll
  for (int k = 0; k < 32; ++k) acol[k] = lsA[k * LDA + t];        // A[k][t]
#pragma unroll
  for (int jj = 0; jj < 8; ++jj) {
    float4 a4 = *((const float4*)&lsA[r * LDA + c0 + 4 * jj]);    // A[r][c0+..]
    arow[4 * jj + 0] = a4.x; arow[4 * jj + 1] = a4.y;
    arow[4 * jj + 2] = a4.z; arow[4 * jj + 3] = a4.w;
  }

  const float xf = xraw[(size_t)n * 64 + t];
  const float bl = (t < 32) ? b[(size_t)n * 32 + t] : 0.f;

  // ================= anchor ADMM =================
  float x_loc = 0.f, s_loc = 0.f;
  float z1 = 0.f, y1 = 0.f;                       // rows t: l=0,u=inf
  float z2 = (t < 32) ? fminf(0.f, bl) : 0.f;     // rows 64+r (lanes<32)
  float y2 = 0.f;
  float z3 = 0.f, y3 = 0.f;                       // lanes 28..31: slack bound rows

#pragma unroll 1
  for (int it = 0; it < ITRS; ++it) {
    float v2 = z2 - y2;                            // meaningful lanes<32
    if (t < 32) lsv2[t] = v2;
    float v3 = z3 - y3;                            // lanes 28..31, local
    __syncthreads();

    // rhs x-part: sig*x + xf + v1 + A^T v2   (v2 via LDS broadcast, 4-way ILP)
    float r10 = fmaf(SIG, x_loc, xf) + (z1 - y1);
    float r11 = 0.f, r12 = 0.f, r13 = 0.f;
#pragma unroll
    for (int kk = 0; kk < 8; ++kk) {
      float4 v4 = ((const float4*)lsv2)[kk];       // broadcast
      r10 = fmaf(acol[4 * kk + 0], v4.x, r10);
      r11 = fmaf(acol[4 * kk + 1], v4.y, r11);
      r12 = fmaf(acol[4 * kk + 2], v4.z, r12);
      r13 = fmaf(acol[4 * kk + 3], v4.w, r13);
    }
    float r1 = (r10 + r11) + (r12 + r13);

    // rhs s-part (meaningful lanes 28..31): sig*s - v[92+i] + v[96+i]
    float r2v = fmaf(SIG, s_loc, v3 - v2);

    // t1 = r1 + C2 * As^T r2   (4 cross-lane scalars, constant lanes)
    float acc = 0.f;
    acc = fmaf(acol[28], rl(r2v, 28), acc);
    acc = fmaf(acol[29], rl(r2v, 29), acc);
    acc = fmaf(acol[30], rl(r2v, 30), acc);
    acc = fmaf(acol[31], rl(r2v, 31), acc);
    lst1[t] = fmaf(C2, acc, r1);
    __syncthreads();

    // x = Sinv * t1  (t1 via LDS broadcast, 4-way ILP)
    float xn0 = 0.f, xn1 = 0.f, xn2 = 0.f, xn3 = 0.f;
#pragma unroll
    for (int jj = 0; jj < 16; ++jj) {
      float4 t4 = ((const float4*)lst1)[jj];       // broadcast
      xn0 = fmaf(Cm[4 * jj + 0], t4.x, xn0);
      xn1 = fmaf(Cm[4 * jj + 1], t4.y, xn1);
      xn2 = fmaf(Cm[4 * jj + 2], t4.z, xn2);
      xn3 = fmaf(Cm[4 * jj + 3], t4.w, xn3);
    }
    float xn = (xn0 + xn1) + (xn2 + xn3);
    x_loc = xn;
    lsx[t] = xn;
    __syncthreads();

    // (A x)[r]: arow in regs, x via 2-addr (free) broadcast reads
    float pa0 = 0.f, pa1 = 0.f, pa2 = 0.f, pa3 = 0.f;
#pragma unroll
    for (int jj = 0; jj < 8; ++jj) {
      float4 x4 = ((const float4*)(lsx + c0))[jj];
      pa0 = fmaf(arow[4 * jj + 0], x4.x, pa0);
      pa1 = fmaf(arow[4 * jj + 1], x4.y, pa1);
      pa2 = fmaf(arow[4 * jj + 2], x4.z, pa2);
      pa3 = fmaf(arow[4 * jj + 3], x4.w, pa3);
    }
    float pa = (pa0 + pa1) + (pa2 + pa3);
    pa += __shfl_xor(pa, 32);

    // s = C2*(r2 + As x)  (meaningful lanes 28..31)
    float s_new = C2 * (r2v + pa);

    // z,y updates
    { float q1 = xn + y1; z1 = fmaxf(q1, 0.f); y1 = q1 - z1; }
    if (t < 32) {
      float Cx2 = pa - ((t >= 28) ? s_new : 0.f);  // rows 92..95: As x - s
      float q2 = Cx2 + y2; z2 = fminf(q2, bl); y2 = q2 - z2;
    }
    s_loc = s_new;
    { float q3 = s_new + y3; z3 = fmaxf(q3, 0.f); y3 = q3 - z3; }  // lanes 28..31
  }
  const float xfeas_r = x_loc;   // lsx still holds x_feas

  // ================= MLP gradient =================
  float4 hacc = make_float4(0.f, 0.f, 0.f, 0.f);
  const float4* W1v = (const float4*)W1;
#pragma unroll 2
  for (int j4 = 0; j4 < 16; ++j4) {
    float4 x4 = ((const float4*)lsx)[j4];          // broadcast
    float xj[4] = {x4.x, x4.y, x4.z, x4.w};
#pragma unroll
    for (int jj = 0; jj < 4; ++jj) {
      float4 w = W1v[(4 * j4 + jj) * 64 + t];
      hacc.x = fmaf(xj[jj], w.x, hacc.x);
      hacc.y = fmaf(xj[jj], w.y, hacc.y);
      hacc.z = fmaf(xj[jj], w.z, hacc.z);
      hacc.w = fmaf(xj[jj], w.w, hacc.w);
    }
  }
  float4 wv = ((const float4*)w2)[t];
  float hx, u0, u1, u2, u3;
  hx = tanhf(hacc.x); u0 = (1.f - hx * hx) * wv.x;
  hx = tanhf(hacc.y); u1 = (1.f - hx * hx) * wv.y;
  hx = tanhf(hacc.z); u2 = (1.f - hx * hx) * wv.z;
  hx = tanhf(hacc.w); u3 = (1.f - hx * hx) * wv.w;
  __syncthreads();                       // lsx readers done
  ((float4*)sbuf)[t] = make_float4(u0, u1, u2, u3);   // sbuf = u[256]
  __syncthreads();

  // g[t] = sum_c W1[t][c]*u[c]; W1T pre-packed: W1T4[c4*64+t] = W1[t][4c4..4c4+3]
  float g0 = 0.f, g1 = 0.f, g2 = 0.f, g3 = 0.f;
  const float4* L4 = (const float4*)W1T;
#pragma unroll 4
  for (int c4 = 0; c4 < 64; ++c4) {
    float4 u4 = ((const float4*)sbuf)[c4];   // broadcast
    float4 w4 = L4[c4 * 64 + t];             // coalesced
    g0 = fmaf(w4.x, u4.x, g0);
    g1 = fmaf(w4.y, u4.y, g1);
    g2 = fmaf(w4.z, u4.z, g2);
    g3 = fmaf(w4.w, u4.w, g3);
  }
  const float gl = (g0 + g1) + (g2 + g3);

  // ================= row norms (from arow registers) =================
  float pr0 = 0.f, pr1 = 0.f, pr2 = 0.f, pr3 = 0.f;
#pragma unroll
  for (int jj = 0; jj < 8; ++jj) {
    pr0 = fmaf(arow[4 * jj + 0], arow[4 * jj + 0], pr0);
    pr1 = fmaf(arow[4 * jj + 1], arow[4 * jj + 1], pr1);
    pr2 = fmaf(arow[4 * jj + 2], arow[4 * jj + 2], pr2);
    pr3 = fmaf(arow[4 * jj + 3], arow[4 * jj + 3], pr3);
  }
  float pr = (pr0 + pr1) + (pr2 + pr3);
  pr += __shfl_xor(pr, 32);
  __syncthreads();                       // u readers done before lsrn write
  if (t < 32) lsrn[t] = 1.0f / fmaxf(sqrtf(pr), 1e-12f);
  __syncthreads();

  const float rcp_r = lsrn[r];           // spread read, conflict-free
  const float bn = (t < 32) ? bl * rcp_r : 0.f;

  // scale register fragments (lsA stays raw)
#pragma unroll
  for (int j = 0; j < 32; ++j) arow[j] *= rcp_r;
#pragma unroll
  for (int k = 0; k < 32; ++k) acol[k] *= lsrn[k];   // broadcast reads, static idx

  // ================= LMO QP: build M, invert =================
  // M col t: (1+eps+sig)I + sum_k rcp_k^2 A[k][t] A[k][:]
#pragma unroll
  for (int i = 0; i < 64; ++i) Cm[i] = 0.f;
#pragma unroll 1
  for (int k = 0; k < 32; ++k) {
    float rn = lsrn[k];                  // broadcast (dynamic k: LDS)
    float ak = lsA[k * LDA + t] * rn * rn;
#pragma unroll
    for (int ii = 0; ii < 16; ++ii) {
      float4 a4 = *((const float4*)&lsA[k * LDA + 4 * ii]);  // raw row, broadcast
      Cm[4 * ii + 0] = fmaf(ak, a4.x, Cm[4 * ii + 0]);
      Cm[4 * ii + 1] = fmaf(ak, a4.y, Cm[4 * ii + 1]);
      Cm[4 * ii + 2] = fmaf(ak, a4.z, Cm[4 * ii + 2]);
      Cm[4 * ii + 3] = fmaf(ak, a4.w, Cm[4 * ii + 3]);
    }
  }
#pragma unroll
  for (int i = 0; i < 64; ++i) Cm[i] += (i == t) ? (1.0f + 1e-4f + SIG) : 0.0f;

  gj_invert(Cm, t);   // Cm[j] = Minv[t][j], zero LDS

  // ================= LMO ADMM =================
  x_loc = 0.f; z1 = 0.f; y1 = 0.f;
  z2 = (t < 32) ? fminf(0.f, bn) : 0.f;
  y2 = 0.f;

#pragma unroll 1
  for (int it = 0; it < ITRS; ++it) {
    if (t < 32) lsv2[t] = z2 - y2;
    __syncthreads();
    float r10 = fmaf(SIG, x_loc, gl) + (z1 - y1);
    float r11 = 0.f, r12 = 0.f, r13 = 0.f;
#pragma unroll
    for (int kk = 0; kk < 8; ++kk) {
      float4 v4 = ((const float4*)lsv2)[kk];       // broadcast
      r10 = fmaf(acol[4 * kk + 0], v4.x, r10);
      r11 = fmaf(acol[4 * kk + 1], v4.y, r11);
      r12 = fmaf(acol[4 * kk + 2], v4.z, r12);
      r13 = fmaf(acol[4 * kk + 3], v4.w, r13);
    }
    lst1[t] = (r10 + r11) + (r12 + r13);
    __syncthreads();

    float xn0 = 0.f, xn1 = 0.f, xn2 = 0.f, xn3 = 0.f;
#pragma unroll
    for (int jj = 0; jj < 16; ++jj) {
      float4 t4 = ((const float4*)lst1)[jj];       // broadcast
      xn0 = fmaf(Cm[4 * jj + 0], t4.x, xn0);
      xn1 = fmaf(Cm[4 * jj + 1], t4.y, xn1);
      xn2 = fmaf(Cm[4 * jj + 2], t4.z, xn2);
      xn3 = fmaf(Cm[4 * jj + 3], t4.w, xn3);
    }
    float xn = (xn0 + xn1) + (xn2 + xn3);
    x_loc = xn;
    lsx[t] = xn;
    __syncthreads();

    // (An x)[r]: arow pre-scaled by rcp_r
    float pa0 = 0.f, pa1 = 0.f, pa2 = 0.f, pa3 = 0.f;
#pragma unroll
    for (int jj = 0; jj < 8; ++jj) {
      float4 x4 = ((const float4*)(lsx + c0))[jj];
      pa0 = fmaf(arow[4 * jj + 0], x4.x, pa0);
      pa1 = fmaf(arow[4 * jj + 1], x4.y, pa1);
      pa2 = fmaf(arow[4 * jj + 2], x4.z, pa2);
      pa3 = fmaf(arow[4 * jj + 3], x4.w, pa3);
    }
    float pa = (pa0 + pa1) + (pa2 + pa3);
    pa += __shfl_xor(pa, 32);

    { float q1 = xn + y1; z1 = fmaxf(q1, 0.f); y1 = q1 - z1; }
    if (t < 32) { float q2 = pa + y2; z2 = fminf(q2, bn); y2 = q2 - z2; }
  }

  out[(size_t)n * 64 + t] = fmaf(0.1f, x_loc, 0.9f * xfeas_r);
}

// ---- W1 re-pack: W1T[c4*256 + t*4 + j] = W1[t*256 + 4*c4 + j] (once) ----
__global__ void w1t_kernel(const float* __restrict__ W1, float* __restrict__ W1T) {
  int idx = blockIdx.x * 256 + threadIdx.x;
  if (idx < 64 * 256) {
    int c4 = idx >> 8, rem = idx & 255, tt = rem >> 2, j = rem & 3;
    W1T[idx] = W1[tt * 256 + 4 * c4 + j];
  }
}

extern "C" void kernel_launch(void* const* d_in, const int* in_sizes, int n_in,
                              void* d_out, int out_size, void* d_ws, size_t ws_size,
                              hipStream_t stream) {
  const float* xraw = (const float*)d_in[0];  // [N,64]
  const float* A    = (const float*)d_in[1];  // [N,32,64]
  const float* b    = (const float*)d_in[2];  // [N,32]
  const float* W1   = (const float*)d_in[3];  // [64,256]
  const float* w2   = (const float*)d_in[4];  // [256]
  float* out = (float*)d_out;

  const int nprob = in_sizes[0] / 64;
  float* W1T = (float*)d_ws;                  // 16384 floats

  w1t_kernel<<<64, 256, 0, stream>>>(W1, W1T);
  fw_kernel<<<nprob, 64, 0, stream>>>(xraw, A, b, W1, W1T, w2, out);
}